// Round 1
// baseline (584.869 us; speedup 1.0000x reference)
//
#include <hip/hip_runtime.h>

typedef unsigned short u16;
typedef __attribute__((ext_vector_type(8))) _Float16 hfrag8;  // 8 f16 = 4 VGPRs (MFMA A/B frag)
typedef __attribute__((ext_vector_type(4))) float f32x4;      // MFMA C/D frag

__device__ __forceinline__ float bu2f(u16 u) { return __uint_as_float(((unsigned)u) << 16); }
__device__ __forceinline__ u16 f2bu(float f) {
    unsigned x = __float_as_uint(f);
    return (u16)((x + 0x7fffu + ((x >> 16) & 1u)) >> 16);   // RNE f32->bf16
}
__device__ __forceinline__ u16 f2hu(float f) {              // f32 -> f16 bit pattern (RNE)
    _Float16 h = (_Float16)f;
    return __builtin_bit_cast(u16, h);
}
__device__ __forceinline__ float ldf(const void* p, int i, bool f32) {
    return f32 ? ((const float*)p)[i] : bu2f(((const u16*)p)[i]);
}
// silu via v_rcp_f32 (1 ulp) instead of IEEE divide chain: ~2x cheaper
__device__ __forceinline__ float siluf(float x) {
    return x * __builtin_amdgcn_rcpf(1.0f + __expf(-x));
}

// ---------------------------------------------------------------------------
// A0: dtype detector (unchanged).
// ---------------------------------------------------------------------------
__global__ void detect_dtype(const void* nf, int* flag)
{
    const int lane = threadIdx.x;
    const u16* p = (const u16*)nf;
    int ext = 0;
    for (int s = 0; s < 4; s++) {
        u16 v = p[(lane * 4 + s) * 2];
        int e = (v >> 7) & 0xFF;
        ext += (e >= 140 || e == 0) ? 1 : 0;
    }
#pragma unroll
    for (int d = 1; d < 64; d <<= 1) ext += __shfl_xor(ext, d);
    if (lane == 0) flag[0] = (ext > 32) ? 1 : 0;   // 1 = float32, 0 = bf16
}

// ---------------------------------------------------------------------------
// PREP (fused): blocks [0,256) = per-node precompute, [256,767) = T table,
// [767,895) = weight transposes. Independent work -> one dispatch, overlaps.
// ---------------------------------------------------------------------------
__global__ __launch_bounds__(256) void prep_kernel(
    const void* __restrict__ coords, const void* __restrict__ nf,
    const void* __restrict__ We1, const void* __restrict__ be1,
    const void* __restrict__ We2, const void* __restrict__ Wc1,
    const int* __restrict__ flag,
    float* __restrict__ cbar, float* __restrict__ pi2, float* __restrict__ qd,
    float* __restrict__ Ttab, u16* __restrict__ We2T, u16* __restrict__ Wc1T)
{
    const bool f32 = flag[0] != 0;
    const int t = threadIdx.x;
    const int blk = blockIdx.x;

    __shared__ float nf_l[4][128];
    __shared__ float ctmp[4][12];
    __shared__ float cb_l[4][3];
    __shared__ float pe[128];
    __shared__ u16 tile[32][33];

    if (blk < 256) {
        // ---- per-node precompute: cbar, pi2, qd ----
        const int row0 = blk * 4;
        for (int idx = t; idx < 512; idx += 256) {
            int r = idx >> 7, k = idx & 127;
            nf_l[r][k] = ldf(nf, (row0 + r) * 128 + k, f32);
        }
        if (t < 48) ctmp[t / 12][t % 12] = ldf(coords, row0 * 12 + t, f32);
        __syncthreads();
        if (t < 12) {
            int r = t / 3, x = t % 3;
            float m = 0.25f * (ctmp[r][x] + ctmp[r][3 + x] + ctmp[r][6 + x] + ctmp[r][9 + x]);
            cb_l[r][x] = m;
            cbar[(row0 + r) * 3 + x] = m;
        }
        __syncthreads();
        const int n = t;
        float accP[4] = {0.f, 0.f, 0.f, 0.f}, accQ[4] = {0.f, 0.f, 0.f, 0.f};
        for (int k = 0; k < 128; k++) {
            float w1 = ldf(We1, k * 256 + n, f32);
            float w2 = ldf(We1, (128 + k) * 256 + n, f32);
#pragma unroll
            for (int r = 0; r < 4; r++) {
                accP[r] += nf_l[r][k] * w1;
                accQ[r] += nf_l[r][k] * w2;
            }
        }
        float wx = ldf(We1, 384 * 256 + n, f32);
        float wy = ldf(We1, 385 * 256 + n, f32);
        float wz = ldf(We1, 386 * 256 + n, f32);
        float b1 = ldf(be1, n, f32);
#pragma unroll
        for (int r = 0; r < 4; r++) {
            float d = cb_l[r][0] * wx + cb_l[r][1] * wy + cb_l[r][2] * wz;
            pi2[(row0 + r) * 256 + n] = accP[r] + d + b1;
            qd[(row0 + r) * 256 + n]  = accQ[r] - d;
        }
    } else if (blk < 767) {
        // ---- T[d+255][n] = sinusoidal_pe(d) @ We1[256:384] ----
        const float d = (float)(blk - 511);           // d in [-255,255]
        if (t < 64) {
            float ang = d * 3.14159265358979323846f * exp2f(-(float)t * 0.125f);
            pe[t] = sinf(ang);
            pe[64 + t] = cosf(ang);
        }
        __syncthreads();
        float acc = 0.f;
        for (int k = 0; k < 128; k++) acc += pe[k] * ldf(We1, (256 + k) * 256 + t, f32);
        Ttab[(blk - 256) * 256 + t] = acc;
    } else {
        // ---- transpose We2, Wc1 (256x256) -> n-major, k-contiguous, f16 ----
        int tbf = blk - 767;
        int mat = tbf >> 6;
        int tb = tbf & 63;
        int bx = tb & 7, by = tb >> 3;
        const void* src = mat ? Wc1 : We2;
        u16* dst = mat ? Wc1T : We2T;
        int tx = threadIdx.x & 31, ty = threadIdx.x >> 5;
#pragma unroll
        for (int p = 0; p < 4; p++) {
            int r = by * 32 + ty + p * 8;
            tile[ty + p * 8][tx] = f2hu(ldf(src, r * 256 + bx * 32 + tx, f32));
        }
        __syncthreads();
#pragma unroll
        for (int p = 0; p < 4; p++) {
            int r = bx * 32 + ty + p * 8;
            dst[r * 256 + by * 32 + tx] = tile[tx][ty + p * 8];
        }
    }
}

// ---------------------------------------------------------------------------
// B: fused edge kernel. One WG per (b,i); loops j in 4 chunks of 64.
// LDS diet: h1/msg share one buffer (extra barrier between p2-kloop and
// msg writes); pi2 slice, agg, coord-partials live in registers. 38 KB LDS
// -> 4 blocks/CU -> all 1024 WGs resident (256 CU x 4).
// ---------------------------------------------------------------------------
__global__ __launch_bounds__(256, 4) void edge_kernel(
    const int* __restrict__ resid,
    const float* __restrict__ pi2, const float* __restrict__ qd,
    const float* __restrict__ Ttab, const float* __restrict__ cbar,
    const u16* __restrict__ We2T, const u16* __restrict__ Wc1T,
    const void* __restrict__ be2, const void* __restrict__ bc1,
    const void* __restrict__ Wc2, const void* __restrict__ bc2,
    const int* __restrict__ flag,
    float* __restrict__ agg_out, float* __restrict__ cupd_out)
{
    const bool f32 = flag[0] != 0;
    const int wg = blockIdx.x;            // b*256 + i
    const int b = wg >> 8;
    const int t = threadIdx.x;
    const int lane = t & 63, w = t >> 6;  // 4 waves; wave w owns cols [64w,64w+64)
    const int c = lane & 15, q = lane >> 4;

    __shared__ __align__(16) u16 hm[64][264];   // h1 / msg alias, f16 bits, pad +8
    __shared__ float be2_l[256], bc1_l[256], wc2_l[256];
    __shared__ int relidx[256];
    __shared__ float fin[4][4];
    __shared__ float cbi[3];

    int ri = resid[(b << 8) + (wg & 255)];
    relidx[t] = ri - resid[(b << 8) + t] + 255;
    be2_l[t] = ldf(be2, t, f32);
    bc1_l[t] = ldf(bc1, t, f32);
    wc2_l[t] = ldf(Wc2, t, f32);
    if (t < 3) cbi[t] = cbar[wg * 3 + t];
    const float bc2q = 0.25f * ldf(bc2, 0, f32);   // bc2 folded per-wave (x4 waves)

    // phase-1 thread mapping: wave w handles j rows [16w,16w+16), lane owns 4 k's
    const int kp = lane << 2;
    const float4 pv = *(const float4*)(pi2 + wg * 256 + kp);  // pi2 slice in regs

    float aggv[4] = {0.f, 0.f, 0.f, 0.f};          // agg cols (valid on q==0)
    float s0 = 0.f, s1 = 0.f, s2 = 0.f, s3 = 0.f;  // deferred coord partials (c==0)
    __syncthreads();

    for (int jc = 0; jc < 4; jc++) {
        const int j0 = jc << 6;
        // ---- phase 1: h1 = silu(pi2[i] + qd[j] + T[rel]), f16 into LDS ----
        {
            const float* qbase = qd + ((b << 8) + j0) * 256 + kp;
#pragma unroll 4
            for (int jj = w * 16; jj < w * 16 + 16; jj++) {
                const float4 qv = *(const float4*)(qbase + jj * 256);
                const float4 tv = *(const float4*)(Ttab + relidx[j0 + jj] * 256 + kp);
                float v0 = siluf(pv.x + qv.x + tv.x);
                float v1 = siluf(pv.y + qv.y + tv.y);
                float v2 = siluf(pv.z + qv.z + tv.z);
                float v3 = siluf(pv.w + qv.w + tv.w);
                uint2 pk;
                pk.x = (unsigned)f2hu(v0) | ((unsigned)f2hu(v1) << 16);
                pk.y = (unsigned)f2hu(v2) | ((unsigned)f2hu(v3) << 16);
                *(uint2*)&hm[jj][kp] = pk;
            }
        }
        __syncthreads();

        // ---- phase 2 k-loop: h1 @ We2 ----
        f32x4 acc[4][4];
        const f32x4 zf = {0.f, 0.f, 0.f, 0.f};
#pragma unroll
        for (int m = 0; m < 4; m++)
#pragma unroll
            for (int n = 0; n < 4; n++) acc[m][n] = zf;
#pragma unroll
        for (int ks = 0; ks < 8; ks++) {
            const int kb = ks * 32 + q * 8;
            hfrag8 a[4], bb[4];
#pragma unroll
            for (int m = 0; m < 4; m++) a[m] = *(const hfrag8*)&hm[m * 16 + c][kb];
#pragma unroll
            for (int n = 0; n < 4; n++)
                bb[n] = *(const hfrag8*)(We2T + (w * 64 + n * 16 + c) * 256 + kb);
#pragma unroll
            for (int m = 0; m < 4; m++)
#pragma unroll
                for (int n = 0; n < 4; n++)
                    acc[m][n] = __builtin_amdgcn_mfma_f32_16x16x32_f16(a[m], bb[n], acc[m][n], 0, 0, 0);
        }
        __syncthreads();   // all waves done reading h1 before msg overwrites it

        // ---- phase 2 epilogue: msg = silu(.+be2) into hm; agg in regs ----
#pragma unroll
        for (int n = 0; n < 4; n++) {
            const int col = w * 64 + n * 16 + c;
            const float bias = be2_l[col];
            float part = 0.f;
#pragma unroll
            for (int m = 0; m < 4; m++) {
#pragma unroll
                for (int r = 0; r < 4; r++) {
                    float s = siluf(acc[m][n][r] + bias);
                    part += s;
                    hm[m * 16 + q * 4 + r][col] = f2hu(s);
                }
            }
            part += __shfl_xor(part, 16);
            part += __shfl_xor(part, 32);
            aggv[n] += part;              // meaningful on q==0 lanes only
        }
        __syncthreads();   // msg ready

        // ---- phase 3 k-loop: msg @ Wc1 ----
#pragma unroll
        for (int m = 0; m < 4; m++)
#pragma unroll
            for (int n = 0; n < 4; n++) acc[m][n] = zf;
#pragma unroll
        for (int ks = 0; ks < 8; ks++) {
            const int kb = ks * 32 + q * 8;
            hfrag8 a[4], bb[4];
#pragma unroll
            for (int m = 0; m < 4; m++) a[m] = *(const hfrag8*)&hm[m * 16 + c][kb];
#pragma unroll
            for (int n = 0; n < 4; n++)
                bb[n] = *(const hfrag8*)(Wc1T + (w * 64 + n * 16 + c) * 256 + kb);
#pragma unroll
            for (int m = 0; m < 4; m++)
#pragma unroll
                for (int n = 0; n < 4; n++)
                    acc[m][n] = __builtin_amdgcn_mfma_f32_16x16x32_f16(a[m], bb[n], acc[m][n], 0, 0, 0);
        }

        // ---- phase 3 epilogue: cu row-dots; deferred distributive coord sums
        //  sum_j cu_j*cbar_j = sum_w sum_j part_wj*cbar_j  (bc2 folded /4)
        float dotv[4][4];
#pragma unroll
        for (int m = 0; m < 4; m++)
#pragma unroll
            for (int r = 0; r < 4; r++) dotv[m][r] = 0.f;
#pragma unroll
        for (int n = 0; n < 4; n++) {
            const int col = w * 64 + n * 16 + c;
            const float bias = bc1_l[col];
            const float wv = wc2_l[col];
#pragma unroll
            for (int m = 0; m < 4; m++)
#pragma unroll
                for (int r = 0; r < 4; r++)
                    dotv[m][r] += siluf(acc[m][n][r] + bias) * wv;
        }
#pragma unroll
        for (int m = 0; m < 4; m++) {
#pragma unroll
            for (int r = 0; r < 4; r++) {
                float v = dotv[m][r];
                v += __shfl_xor(v, 1);
                v += __shfl_xor(v, 2);
                v += __shfl_xor(v, 4);
                v += __shfl_xor(v, 8);
                if (c == 0) {   // wave-partial cu for j = j0 + m*16 + q*4 + r
                    const float vb = v + bc2q;
                    const float* cp = cbar + ((b << 8) + j0 + m * 16 + q * 4 + r) * 3;
                    s0 += vb;
                    s1 += vb * cp[0];
                    s2 += vb * cp[1];
                    s3 += vb * cp[2];
                }
            }
        }
        __syncthreads();   // all waves done reading msg; next p1 may overwrite
    }

    // ---- agg out (each wave owns its 64 cols; q==0 lanes hold col sums) ----
    if (q == 0) {
#pragma unroll
        for (int n = 0; n < 4; n++)
            agg_out[wg * 256 + w * 64 + n * 16 + c] = aggv[n];
    }

    // ---- final coord reduction: one wave-reduce + 16-float LDS exchange ----
#pragma unroll
    for (int d = 1; d < 64; d <<= 1) {
        s0 += __shfl_xor(s0, d);
        s1 += __shfl_xor(s1, d);
        s2 += __shfl_xor(s2, d);
        s3 += __shfl_xor(s3, d);
    }
    if (lane == 0) { fin[w][0] = s0; fin[w][1] = s1; fin[w][2] = s2; fin[w][3] = s3; }
    __syncthreads();
    if (t == 0) {
        float S0 = fin[0][0] + fin[1][0] + fin[2][0] + fin[3][0];
        float S1 = fin[0][1] + fin[1][1] + fin[2][1] + fin[3][1];
        float S2 = fin[0][2] + fin[1][2] + fin[2][2] + fin[3][2];
        float S3 = fin[0][3] + fin[1][3] + fin[2][3] + fin[3][3];
        // coord_upd = (sum cu)*cbar_i - sum(cu*cbar_j)
        cupd_out[wg * 3 + 0] = S0 * cbi[0] - S1;
        cupd_out[wg * 3 + 1] = S0 * cbi[1] - S2;
        cupd_out[wg * 3 + 2] = S0 * cbi[2] - S3;
    }
}

// ---------------------------------------------------------------------------
// OUT (fused): blocks [0,128) = node MLP + LayerNorm -> d_out[12288..],
// blocks [128,176) = updated coords -> d_out[0..12288).
// ---------------------------------------------------------------------------
__global__ __launch_bounds__(256) void out_kernel(
    const void* __restrict__ nf, const float* __restrict__ agg,
    const void* __restrict__ Wn1, const void* __restrict__ bn1,
    const void* __restrict__ Wn2, const void* __restrict__ bn2,
    const void* __restrict__ gamma, const void* __restrict__ beta,
    const void* __restrict__ coords, const void* __restrict__ mask,
    const float* __restrict__ cupd, const int* __restrict__ flag,
    void* __restrict__ d_out)
{
    const bool f32 = flag[0] != 0;
    const int t = threadIdx.x;

    if (blockIdx.x >= 128) {
        // ---- coords part ----
        int idx = (blockIdx.x - 128) * 256 + t;
        if (idx < 4 * 256 * 4 * 3) {
            int x = idx % 3;
            int a = (idx / 3) & 3;
            int node = idx / 12;
            float v = ldf(coords, idx, f32) + cupd[node * 3 + x] * ldf(mask, node * 4 + a, f32);
            if (f32) ((float*)d_out)[idx] = v;
            else     ((u16*)d_out)[idx] = f2bu(v);
        }
        return;
    }

    // ---- node MLP + LN ----
    const int row0 = blockIdx.x * 8;
    __shared__ float x_l[8][384];
    __shared__ float hs[8][256];
    __shared__ float ho[8][128];
    for (int idx = t; idx < 8 * 384; idx += 256) {
        int r = idx / 384, k = idx % 384;
        x_l[r][k] = (k < 128) ? ldf(nf, (row0 + r) * 128 + k, f32)
                              : agg[(row0 + r) * 256 + (k - 128)];
    }
    __syncthreads();
    {
        float a1[8] = {0.f, 0.f, 0.f, 0.f, 0.f, 0.f, 0.f, 0.f};
        for (int k = 0; k < 384; k++) {
            float wv = ldf(Wn1, k * 256 + t, f32);
#pragma unroll
            for (int r = 0; r < 8; r++) a1[r] += x_l[r][k] * wv;
        }
        float b1 = ldf(bn1, t, f32);
#pragma unroll
        for (int r = 0; r < 8; r++) hs[r][t] = siluf(a1[r] + b1);
    }
    __syncthreads();
    {
        int cc = t & 127, rg = (t >> 7) * 4;
        float a2[4] = {0.f, 0.f, 0.f, 0.f};
        for (int k = 0; k < 256; k++) {
            float wv = ldf(Wn2, k * 128 + cc, f32);
#pragma unroll
            for (int r = 0; r < 4; r++) a2[r] += hs[rg + r][k] * wv;
        }
        float b2 = ldf(bn2, cc, f32);
#pragma unroll
        for (int r = 0; r < 4; r++) ho[rg + r][cc] = a2[r] + b2;
    }
    __syncthreads();
    {
        int row = t >> 5, s = t & 31;
        float sm = 0.f, sq = 0.f;
#pragma unroll
        for (int u = 0; u < 4; u++) {
            float v = ho[row][s + 32 * u];
            sm += v; sq += v * v;
        }
#pragma unroll
        for (int d = 1; d < 32; d <<= 1) {
            sm += __shfl_xor(sm, d);
            sq += __shfl_xor(sq, d);
        }
        float mu = sm * (1.f / 128.f);
        float var = sq * (1.f / 128.f) - mu * mu;
        float inv = rsqrtf(var + 1e-5f);
#pragma unroll
        for (int u = 0; u < 4; u++) {
            int cc = s + 32 * u;
            float y = (ho[row][cc] - mu) * inv;
            float outv = y * ldf(gamma, cc, f32) + ldf(beta, cc, f32);
            int oi = 12288 + (row0 + row) * 128 + cc;
            if (f32) ((float*)d_out)[oi] = outv;
            else     ((u16*)d_out)[oi] = f2bu(outv);
        }
    }
}

extern "C" void kernel_launch(void* const* d_in, const int* in_sizes, int n_in,
                              void* d_out, int out_size, void* d_ws, size_t ws_size,
                              hipStream_t stream)
{
    const void* coords = d_in[0];
    const void* nf     = d_in[1];
    const void* mask   = d_in[2];
    const int* resid   = (const int*)d_in[3];
    const void* We1 = d_in[4];
    const void* be1 = d_in[5];
    const void* We2 = d_in[6];
    const void* be2 = d_in[7];
    const void* Wn1 = d_in[8];
    const void* bn1 = d_in[9];
    const void* Wn2 = d_in[10];
    const void* bn2 = d_in[11];
    const void* gamma = d_in[12];
    const void* beta  = d_in[13];
    const void* Wc1 = d_in[14];
    const void* bc1 = d_in[15];
    const void* Wc2 = d_in[16];
    const void* bc2 = d_in[17];

    // workspace layout: [flag(16 floats pad)][f32 arrays][f16 weight arrays] ~3.96 MB
    int* flag  = (int*)d_ws;
    float* f   = (float*)d_ws + 16;
    float* cbar = f;                 // 1024*3
    float* pi2  = cbar + 3072;       // 1024*256
    float* qd   = pi2 + 262144;      // 1024*256
    float* Ttab = qd + 262144;       // 511*256
    float* agg  = Ttab + 130816;     // 1024*256
    float* cupd = agg + 262144;      // 1024*3
    u16* We2T = (u16*)(cupd + 3072); // 256*256 f16
    u16* Wc1T = We2T + 65536;        // 256*256 f16

    hipLaunchKernelGGL(detect_dtype, dim3(1), dim3(64), 0, stream, nf, flag);
    hipLaunchKernelGGL(prep_kernel, dim3(895), dim3(256), 0, stream,
                       coords, nf, We1, be1, We2, Wc1, flag, cbar, pi2, qd, Ttab, We2T, Wc1T);
    hipLaunchKernelGGL(edge_kernel, dim3(1024), dim3(256), 0, stream,
                       resid, pi2, qd, Ttab, cbar, We2T, Wc1T, be2, bc1, Wc2, bc2, flag, agg, cupd);
    hipLaunchKernelGGL(out_kernel, dim3(176), dim3(256), 0, stream,
                       nf, agg, Wn1, bn1, Wn2, bn2, gamma, beta, coords, mask, cupd, flag, d_out);
}

// Round 4
// 568.857 us; speedup vs baseline: 1.0281x; 1.0281x over previous
//
#include <hip/hip_runtime.h>

typedef unsigned short u16;
typedef __attribute__((ext_vector_type(8))) _Float16 hfrag8;  // 8 f16 = 4 VGPRs (MFMA A/B frag)
typedef __attribute__((ext_vector_type(4))) float f32x4;      // MFMA C/D frag

__device__ __forceinline__ float bu2f(u16 u) { return __uint_as_float(((unsigned)u) << 16); }
__device__ __forceinline__ u16 f2bu(float f) {
    unsigned x = __float_as_uint(f);
    return (u16)((x + 0x7fffu + ((x >> 16) & 1u)) >> 16);   // RNE f32->bf16
}
__device__ __forceinline__ u16 f2hu(float f) {              // f32 -> f16 bit pattern (RNE)
    _Float16 h = (_Float16)f;
    return __builtin_bit_cast(u16, h);
}
__device__ __forceinline__ float ldf(const void* p, int i, bool f32) {
    return f32 ? ((const float*)p)[i] : bu2f(((const u16*)p)[i]);
}
// silu via v_rcp_f32 (1 ulp) instead of IEEE divide chain
__device__ __forceinline__ float siluf(float x) {
    return x * __builtin_amdgcn_rcpf(1.0f + __expf(-x));
}
// packed f32x2 -> f16x2 bits (v_cvt_pkrtz_f16_f32)
__device__ __forceinline__ unsigned pkh(float a, float b) {
    return __builtin_bit_cast(unsigned, __builtin_amdgcn_cvt_pkrtz(a, b));
}

// ---------------------------------------------------------------------------
// A0: dtype detector (unchanged).
// ---------------------------------------------------------------------------
__global__ void detect_dtype(const void* nf, int* flag)
{
    const int lane = threadIdx.x;
    const u16* p = (const u16*)nf;
    int ext = 0;
    for (int s = 0; s < 4; s++) {
        u16 v = p[(lane * 4 + s) * 2];
        int e = (v >> 7) & 0xFF;
        ext += (e >= 140 || e == 0) ? 1 : 0;
    }
#pragma unroll
    for (int d = 1; d < 64; d <<= 1) ext += __shfl_xor(ext, d);
    if (lane == 0) flag[0] = (ext > 32) ? 1 : 0;   // 1 = float32, 0 = bf16
}

// ---------------------------------------------------------------------------
// PREP (fused): blocks [0,256) = per-node precompute, [256,767) = T table,
// [767,895) = weight transposes.
// ---------------------------------------------------------------------------
__global__ __launch_bounds__(256) void prep_kernel(
    const void* __restrict__ coords, const void* __restrict__ nf,
    const void* __restrict__ We1, const void* __restrict__ be1,
    const void* __restrict__ We2, const void* __restrict__ Wc1,
    const int* __restrict__ flag,
    float* __restrict__ cbar, float* __restrict__ pi2, float* __restrict__ qd,
    float* __restrict__ Ttab, u16* __restrict__ We2T, u16* __restrict__ Wc1T)
{
    const bool f32 = flag[0] != 0;
    const int t = threadIdx.x;
    const int blk = blockIdx.x;

    __shared__ float nf_l[4][128];
    __shared__ float ctmp[4][12];
    __shared__ float cb_l[4][3];
    __shared__ float pe[128];
    __shared__ u16 tile[32][33];

    if (blk < 256) {
        // ---- per-node precompute: cbar, pi2, qd ----
        const int row0 = blk * 4;
        for (int idx = t; idx < 512; idx += 256) {
            int r = idx >> 7, k = idx & 127;
            nf_l[r][k] = ldf(nf, (row0 + r) * 128 + k, f32);
        }
        if (t < 48) ctmp[t / 12][t % 12] = ldf(coords, row0 * 12 + t, f32);
        __syncthreads();
        if (t < 12) {
            int r = t / 3, x = t % 3;
            float m = 0.25f * (ctmp[r][x] + ctmp[r][3 + x] + ctmp[r][6 + x] + ctmp[r][9 + x]);
            cb_l[r][x] = m;
            cbar[(row0 + r) * 3 + x] = m;
        }
        __syncthreads();
        const int n = t;
        float accP[4] = {0.f, 0.f, 0.f, 0.f}, accQ[4] = {0.f, 0.f, 0.f, 0.f};
        for (int k = 0; k < 128; k++) {
            float w1 = ldf(We1, k * 256 + n, f32);
            float w2 = ldf(We1, (128 + k) * 256 + n, f32);
#pragma unroll
            for (int r = 0; r < 4; r++) {
                accP[r] += nf_l[r][k] * w1;
                accQ[r] += nf_l[r][k] * w2;
            }
        }
        float wx = ldf(We1, 384 * 256 + n, f32);
        float wy = ldf(We1, 385 * 256 + n, f32);
        float wz = ldf(We1, 386 * 256 + n, f32);
        float b1 = ldf(be1, n, f32);
#pragma unroll
        for (int r = 0; r < 4; r++) {
            float d = cb_l[r][0] * wx + cb_l[r][1] * wy + cb_l[r][2] * wz;
            pi2[(row0 + r) * 256 + n] = accP[r] + d + b1;
            qd[(row0 + r) * 256 + n]  = accQ[r] - d;
        }
    } else if (blk < 767) {
        // ---- T[d+255][n] = sinusoidal_pe(d) @ We1[256:384] ----
        const float d = (float)(blk - 511);           // d in [-255,255]
        if (t < 64) {
            float ang = d * 3.14159265358979323846f * exp2f(-(float)t * 0.125f);
            pe[t] = sinf(ang);
            pe[64 + t] = cosf(ang);
        }
        __syncthreads();
        float acc = 0.f;
        for (int k = 0; k < 128; k++) acc += pe[k] * ldf(We1, (256 + k) * 256 + t, f32);
        Ttab[(blk - 256) * 256 + t] = acc;
    } else {
        // ---- transpose We2, Wc1 (256x256) -> n-major, k-contiguous, f16 ----
        int tbf = blk - 767;
        int mat = tbf >> 6;
        int tb = tbf & 63;
        int bx = tb & 7, by = tb >> 3;
        const void* src = mat ? Wc1 : We2;
        u16* dst = mat ? Wc1T : We2T;
        int tx = threadIdx.x & 31, ty = threadIdx.x >> 5;
#pragma unroll
        for (int p = 0; p < 4; p++) {
            int r = by * 32 + ty + p * 8;
            tile[ty + p * 8][tx] = f2hu(ldf(src, r * 256 + bx * 32 + tx, f32));
        }
        __syncthreads();
#pragma unroll
        for (int p = 0; p < 4; p++) {
            int r = bx * 32 + ty + p * 8;
            dst[r * 256 + by * 32 + tx] = tile[tx][ty + p * 8];
        }
    }
}

// ---------------------------------------------------------------------------
// B: fused edge kernel. One WG per (b,i); loops j in 8 chunks of 32.
// 32-row chunks -> acc[2][4] (32 VGPR) -> fits 128-VGPR budget without
// spill at 4 blocks/CU. Dual LDS buffers (H=h1, M=msg) -> only 2 barriers
// per chunk. ~38 KB LDS -> 4 blocks/CU resident (whole grid co-resident).
// ---------------------------------------------------------------------------
__global__ __launch_bounds__(256)
__attribute__((amdgpu_waves_per_eu(3, 4)))
void edge_kernel(
    const int* __restrict__ resid,
    const float* __restrict__ pi2, const float* __restrict__ qd,
    const float* __restrict__ Ttab, const float* __restrict__ cbar,
    const u16* __restrict__ We2T, const u16* __restrict__ Wc1T,
    const void* __restrict__ be2, const void* __restrict__ bc1,
    const void* __restrict__ Wc2, const void* __restrict__ bc2,
    const int* __restrict__ flag,
    float* __restrict__ agg_out, float* __restrict__ cupd_out)
{
    const bool f32 = flag[0] != 0;
    const int wg = blockIdx.x;            // b*256 + i
    const int b = wg >> 8;
    const int t = threadIdx.x;
    const int lane = t & 63, w = t >> 6;  // 4 waves; wave w owns cols [64w,64w+64)
    const int c = lane & 15, q = lane >> 4;

    __shared__ __align__(16) u16 H[32][264];   // h1, f16 bits, pad +8
    __shared__ __align__(16) u16 M[32][264];   // msg, f16 bits, pad +8
    __shared__ float be2_l[256], bc1_l[256], wc2_l[256];
    __shared__ int relidx[256];
    __shared__ float fin[4][4];
    __shared__ float cbi[3];

    int ri = resid[(b << 8) + (wg & 255)];
    relidx[t] = ri - resid[(b << 8) + t] + 255;
    be2_l[t] = ldf(be2, t, f32);
    bc1_l[t] = ldf(bc1, t, f32);
    wc2_l[t] = ldf(Wc2, t, f32);
    if (t < 3) cbi[t] = cbar[wg * 3 + t];
    const float bc2q = 0.25f * ldf(bc2, 0, f32);   // bc2 folded per-wave (x4 waves)

    // phase-1 mapping: wave w owns rows [8w,8w+8); lane owns 4 k's
    const int kp = lane << 2;
    const float4 pv = *(const float4*)(pi2 + wg * 256 + kp);  // pi2 slice in regs

    float aggv[4] = {0.f, 0.f, 0.f, 0.f};          // agg cols (valid on q==0)
    float s0 = 0.f, s1 = 0.f, s2 = 0.f, s3 = 0.f;  // deferred coord partials (c==0)
    __syncthreads();

    const f32x4 zf = {0.f, 0.f, 0.f, 0.f};

    for (int jc = 0; jc < 8; jc++) {
        const int j0 = jc << 5;
        // ---- P1: H = silu(pi2[i] + qd[j] + T[rel]), f16 into LDS ----
        {
            const float* qbase = qd + ((b << 8) + j0) * 256 + kp;
            const int r0 = w * 8;
#pragma unroll
            for (int jj = 0; jj < 8; jj++) {
                const int j = r0 + jj;
                const float4 qv = *(const float4*)(qbase + j * 256);
                const float4 tv = *(const float4*)(Ttab + relidx[j0 + j] * 256 + kp);
                uint2 pk;
                pk.x = pkh(siluf(pv.x + qv.x + tv.x), siluf(pv.y + qv.y + tv.y));
                pk.y = pkh(siluf(pv.z + qv.z + tv.z), siluf(pv.w + qv.w + tv.w));
                *(uint2*)&H[j][kp] = pk;
            }
        }
        __syncthreads();   // S1: H complete (also: everyone left prev P3k/M)

        // ---- P2 k-loop: H @ We2 ----
        f32x4 acc[2][4];
#pragma unroll
        for (int m = 0; m < 2; m++)
#pragma unroll
            for (int n = 0; n < 4; n++) acc[m][n] = zf;
#pragma unroll
        for (int ks = 0; ks < 8; ks++) {
            const int kb = ks * 32 + q * 8;
            hfrag8 a[2], bb[4];
            a[0] = *(const hfrag8*)&H[c][kb];
            a[1] = *(const hfrag8*)&H[16 + c][kb];
#pragma unroll
            for (int n = 0; n < 4; n++)
                bb[n] = *(const hfrag8*)(We2T + (w * 64 + n * 16 + c) * 256 + kb);
#pragma unroll
            for (int m = 0; m < 2; m++)
#pragma unroll
                for (int n = 0; n < 4; n++)
                    acc[m][n] = __builtin_amdgcn_mfma_f32_16x16x32_f16(a[m], bb[n], acc[m][n], 0, 0, 0);
        }

        // ---- P2 epilogue: M = silu(.+be2); agg in regs (writes M, not H) ----
#pragma unroll
        for (int n = 0; n < 4; n++) {
            const int col = w * 64 + n * 16 + c;
            const float bias = be2_l[col];
            float part = 0.f;
#pragma unroll
            for (int m = 0; m < 2; m++) {
#pragma unroll
                for (int r = 0; r < 4; r++) {
                    float s = siluf(acc[m][n][r] + bias);
                    part += s;
                    M[m * 16 + q * 4 + r][col] = f2hu(s);
                }
            }
            part += __shfl_xor(part, 16);
            part += __shfl_xor(part, 32);
            aggv[n] += part;              // meaningful on q==0 lanes only
        }
        __syncthreads();   // S2: M complete

        // ---- P3 k-loop: M @ Wc1 ----
#pragma unroll
        for (int m = 0; m < 2; m++)
#pragma unroll
            for (int n = 0; n < 4; n++) acc[m][n] = zf;
#pragma unroll
        for (int ks = 0; ks < 8; ks++) {
            const int kb = ks * 32 + q * 8;
            hfrag8 a[2], bb[4];
            a[0] = *(const hfrag8*)&M[c][kb];
            a[1] = *(const hfrag8*)&M[16 + c][kb];
#pragma unroll
            for (int n = 0; n < 4; n++)
                bb[n] = *(const hfrag8*)(Wc1T + (w * 64 + n * 16 + c) * 256 + kb);
#pragma unroll
            for (int m = 0; m < 2; m++)
#pragma unroll
                for (int n = 0; n < 4; n++)
                    acc[m][n] = __builtin_amdgcn_mfma_f32_16x16x32_f16(a[m], bb[n], acc[m][n], 0, 0, 0);
        }

        // ---- P3 epilogue: cu row-dots; deferred distributive coord sums ----
        float dotv[2][4];
#pragma unroll
        for (int m = 0; m < 2; m++)
#pragma unroll
            for (int r = 0; r < 4; r++) dotv[m][r] = 0.f;
#pragma unroll
        for (int n = 0; n < 4; n++) {
            const int col = w * 64 + n * 16 + c;
            const float bias = bc1_l[col];
            const float wv = wc2_l[col];
#pragma unroll
            for (int m = 0; m < 2; m++)
#pragma unroll
                for (int r = 0; r < 4; r++)
                    dotv[m][r] += siluf(acc[m][n][r] + bias) * wv;
        }
#pragma unroll
        for (int m = 0; m < 2; m++) {
#pragma unroll
            for (int r = 0; r < 4; r++) {
                float v = dotv[m][r];
                v += __shfl_xor(v, 1);
                v += __shfl_xor(v, 2);
                v += __shfl_xor(v, 4);
                v += __shfl_xor(v, 8);
                if (c == 0) {   // wave-partial cu for j = j0 + m*16 + q*4 + r
                    const float vb = v + bc2q;
                    const float* cp = cbar + ((b << 8) + j0 + m * 16 + q * 4 + r) * 3;
                    s0 += vb;
                    s1 += vb * cp[0];
                    s2 += vb * cp[1];
                    s3 += vb * cp[2];
                }
            }
        }
        // no barrier needed here: next P1 writes H (nobody reads H now),
        // and M-readers all passed S2 before any wave can reach next S1.
    }

    // ---- agg out (each wave owns its 64 cols; q==0 lanes hold col sums) ----
    if (q == 0) {
#pragma unroll
        for (int n = 0; n < 4; n++)
            agg_out[wg * 256 + w * 64 + n * 16 + c] = aggv[n];
    }

    // ---- final coord reduction: one wave-reduce + 16-float LDS exchange ----
#pragma unroll
    for (int d = 1; d < 64; d <<= 1) {
        s0 += __shfl_xor(s0, d);
        s1 += __shfl_xor(s1, d);
        s2 += __shfl_xor(s2, d);
        s3 += __shfl_xor(s3, d);
    }
    if (lane == 0) { fin[w][0] = s0; fin[w][1] = s1; fin[w][2] = s2; fin[w][3] = s3; }
    __syncthreads();
    if (t == 0) {
        float S0 = fin[0][0] + fin[1][0] + fin[2][0] + fin[3][0];
        float S1 = fin[0][1] + fin[1][1] + fin[2][1] + fin[3][1];
        float S2 = fin[0][2] + fin[1][2] + fin[2][2] + fin[3][2];
        float S3 = fin[0][3] + fin[1][3] + fin[2][3] + fin[3][3];
        // coord_upd = (sum cu)*cbar_i - sum(cu*cbar_j)
        cupd_out[wg * 3 + 0] = S0 * cbi[0] - S1;
        cupd_out[wg * 3 + 1] = S0 * cbi[1] - S2;
        cupd_out[wg * 3 + 2] = S0 * cbi[2] - S3;
    }
}

// ---------------------------------------------------------------------------
// OUT (fused): blocks [0,128) = node MLP + LayerNorm -> d_out[12288..],
// blocks [128,176) = updated coords -> d_out[0..12288).
// ---------------------------------------------------------------------------
__global__ __launch_bounds__(256) void out_kernel(
    const void* __restrict__ nf, const float* __restrict__ agg,
    const void* __restrict__ Wn1, const void* __restrict__ bn1,
    const void* __restrict__ Wn2, const void* __restrict__ bn2,
    const void* __restrict__ gamma, const void* __restrict__ beta,
    const void* __restrict__ coords, const void* __restrict__ mask,
    const float* __restrict__ cupd, const int* __restrict__ flag,
    void* __restrict__ d_out)
{
    const bool f32 = flag[0] != 0;
    const int t = threadIdx.x;

    if (blockIdx.x >= 128) {
        // ---- coords part ----
        int idx = (blockIdx.x - 128) * 256 + t;
        if (idx < 4 * 256 * 4 * 3) {
            int x = idx % 3;
            int a = (idx / 3) & 3;
            int node = idx / 12;
            float v = ldf(coords, idx, f32) + cupd[node * 3 + x] * ldf(mask, node * 4 + a, f32);
            if (f32) ((float*)d_out)[idx] = v;
            else     ((u16*)d_out)[idx] = f2bu(v);
        }
        return;
    }

    // ---- node MLP + LN ----
    const int row0 = blockIdx.x * 8;
    __shared__ float x_l[8][384];
    __shared__ float hs[8][256];
    __shared__ float ho[8][128];
    for (int idx = t; idx < 8 * 384; idx += 256) {
        int r = idx / 384, k = idx % 384;
        x_l[r][k] = (k < 128) ? ldf(nf, (row0 + r) * 128 + k, f32)
                              : agg[(row0 + r) * 256 + (k - 128)];
    }
    __syncthreads();
    {
        float a1[8] = {0.f, 0.f, 0.f, 0.f, 0.f, 0.f, 0.f, 0.f};
        for (int k = 0; k < 384; k++) {
            float wv = ldf(Wn1, k * 256 + t, f32);
#pragma unroll
            for (int r = 0; r < 8; r++) a1[r] += x_l[r][k] * wv;
        }
        float b1 = ldf(bn1, t, f32);
#pragma unroll
        for (int r = 0; r < 8; r++) hs[r][t] = siluf(a1[r] + b1);
    }
    __syncthreads();
    {
        int cc = t & 127, rg = (t >> 7) * 4;
        float a2[4] = {0.f, 0.f, 0.f, 0.f};
        for (int k = 0; k < 256; k++) {
            float wv = ldf(Wn2, k * 128 + cc, f32);
#pragma unroll
            for (int r = 0; r < 4; r++) a2[r] += hs[rg + r][k] * wv;
        }
        float b2 = ldf(bn2, cc, f32);
#pragma unroll
        for (int r = 0; r < 4; r++) ho[rg + r][cc] = a2[r] + b2;
    }
    __syncthreads();
    {
        int row = t >> 5, s = t & 31;
        float sm = 0.f, sq = 0.f;
#pragma unroll
        for (int u = 0; u < 4; u++) {
            float v = ho[row][s + 32 * u];
            sm += v; sq += v * v;
        }
#pragma unroll
        for (int d = 1; d < 32; d <<= 1) {
            sm += __shfl_xor(sm, d);
            sq += __shfl_xor(sq, d);
        }
        float mu = sm * (1.f / 128.f);
        float var = sq * (1.f / 128.f) - mu * mu;
        float inv = rsqrtf(var + 1e-5f);
#pragma unroll
        for (int u = 0; u < 4; u++) {
            int cc = s + 32 * u;
            float y = (ho[row][cc] - mu) * inv;
            float outv = y * ldf(gamma, cc, f32) + ldf(beta, cc, f32);
            int oi = 12288 + (row0 + row) * 128 + cc;
            if (f32) ((float*)d_out)[oi] = outv;
            else     ((u16*)d_out)[oi] = f2bu(outv);
        }
    }
}

extern "C" void kernel_launch(void* const* d_in, const int* in_sizes, int n_in,
                              void* d_out, int out_size, void* d_ws, size_t ws_size,
                              hipStream_t stream)
{
    const void* coords = d_in[0];
    const void* nf     = d_in[1];
    const void* mask   = d_in[2];
    const int* resid   = (const int*)d_in[3];
    const void* We1 = d_in[4];
    const void* be1 = d_in[5];
    const void* We2 = d_in[6];
    const void* be2 = d_in[7];
    const void* Wn1 = d_in[8];
    const void* bn1 = d_in[9];
    const void* Wn2 = d_in[10];
    const void* bn2 = d_in[11];
    const void* gamma = d_in[12];
    const void* beta  = d_in[13];
    const void* Wc1 = d_in[14];
    const void* bc1 = d_in[15];
    const void* Wc2 = d_in[16];
    const void* bc2 = d_in[17];

    // workspace layout: [flag(16 floats pad)][f32 arrays][f16 weight arrays] ~3.96 MB
    int* flag  = (int*)d_ws;
    float* f   = (float*)d_ws + 16;
    float* cbar = f;                 // 1024*3
    float* pi2  = cbar + 3072;       // 1024*256
    float* qd   = pi2 + 262144;      // 1024*256
    float* Ttab = qd + 262144;       // 511*256
    float* agg  = Ttab + 130816;     // 1024*256
    float* cupd = agg + 262144;      // 1024*3
    u16* We2T = (u16*)(cupd + 3072); // 256*256 f16
    u16* Wc1T = We2T + 65536;        // 256*256 f16

    hipLaunchKernelGGL(detect_dtype, dim3(1), dim3(64), 0, stream, nf, flag);
    hipLaunchKernelGGL(prep_kernel, dim3(895), dim3(256), 0, stream,
                       coords, nf, We1, be1, We2, Wc1, flag, cbar, pi2, qd, Ttab, We2T, Wc1T);
    hipLaunchKernelGGL(edge_kernel, dim3(1024), dim3(256), 0, stream,
                       resid, pi2, qd, Ttab, cbar, We2T, Wc1T, be2, bc1, Wc2, bc2, flag, agg, cupd);
    hipLaunchKernelGGL(out_kernel, dim3(176), dim3(256), 0, stream,
                       nf, agg, Wn1, bn1, Wn2, bn2, gamma, beta, coords, mask, cupd, flag, d_out);
}

// Round 5
// 454.294 us; speedup vs baseline: 1.2874x; 1.2522x over previous
//
#include <hip/hip_runtime.h>

typedef unsigned short u16;
typedef __attribute__((ext_vector_type(8))) _Float16 hfrag8;  // 8 f16 = 4 VGPRs (MFMA A/B frag)
typedef __attribute__((ext_vector_type(4))) float f32x4;      // MFMA C/D frag

__device__ __forceinline__ float bu2f(u16 u) { return __uint_as_float(((unsigned)u) << 16); }
__device__ __forceinline__ u16 f2bu(float f) {
    unsigned x = __float_as_uint(f);
    return (u16)((x + 0x7fffu + ((x >> 16) & 1u)) >> 16);   // RNE f32->bf16
}
__device__ __forceinline__ u16 f2hu(float f) {              // f32 -> f16 bit pattern (RNE)
    _Float16 h = (_Float16)f;
    return __builtin_bit_cast(u16, h);
}
__device__ __forceinline__ float ldf(const void* p, int i, bool f32) {
    return f32 ? ((const float*)p)[i] : bu2f(((const u16*)p)[i]);
}
// silu via v_rcp_f32 (1 ulp) instead of IEEE divide chain
__device__ __forceinline__ float siluf(float x) {
    return x * __builtin_amdgcn_rcpf(1.0f + __expf(-x));
}
// packed f32x2 -> f16x2 bits (v_cvt_pkrtz_f16_f32)
__device__ __forceinline__ unsigned pkh(float a, float b) {
    return __builtin_bit_cast(unsigned, __builtin_amdgcn_cvt_pkrtz(a, b));
}

// ---------------------------------------------------------------------------
// A0: dtype detector (unchanged).
// ---------------------------------------------------------------------------
__global__ void detect_dtype(const void* nf, int* flag)
{
    const int lane = threadIdx.x;
    const u16* p = (const u16*)nf;
    int ext = 0;
    for (int s = 0; s < 4; s++) {
        u16 v = p[(lane * 4 + s) * 2];
        int e = (v >> 7) & 0xFF;
        ext += (e >= 140 || e == 0) ? 1 : 0;
    }
#pragma unroll
    for (int d = 1; d < 64; d <<= 1) ext += __shfl_xor(ext, d);
    if (lane == 0) flag[0] = (ext > 32) ? 1 : 0;   // 1 = float32, 0 = bf16
}

// ---------------------------------------------------------------------------
// PREP (fused): blocks [0,256) = per-node precompute, [256,767) = T table,
// [767,895) = weight transposes.
// ---------------------------------------------------------------------------
__global__ __launch_bounds__(256) void prep_kernel(
    const void* __restrict__ coords, const void* __restrict__ nf,
    const void* __restrict__ We1, const void* __restrict__ be1,
    const void* __restrict__ We2, const void* __restrict__ Wc1,
    const int* __restrict__ flag,
    float* __restrict__ cbar, float* __restrict__ pi2, float* __restrict__ qd,
    float* __restrict__ Ttab, u16* __restrict__ We2T, u16* __restrict__ Wc1T)
{
    const bool f32 = flag[0] != 0;
    const int t = threadIdx.x;
    const int blk = blockIdx.x;

    __shared__ float nf_l[4][128];
    __shared__ float ctmp[4][12];
    __shared__ float cb_l[4][3];
    __shared__ float pe[128];
    __shared__ u16 tile[32][33];

    if (blk < 256) {
        // ---- per-node precompute: cbar, pi2, qd ----
        const int row0 = blk * 4;
        for (int idx = t; idx < 512; idx += 256) {
            int r = idx >> 7, k = idx & 127;
            nf_l[r][k] = ldf(nf, (row0 + r) * 128 + k, f32);
        }
        if (t < 48) ctmp[t / 12][t % 12] = ldf(coords, row0 * 12 + t, f32);
        __syncthreads();
        if (t < 12) {
            int r = t / 3, x = t % 3;
            float m = 0.25f * (ctmp[r][x] + ctmp[r][3 + x] + ctmp[r][6 + x] + ctmp[r][9 + x]);
            cb_l[r][x] = m;
            cbar[(row0 + r) * 3 + x] = m;
        }
        __syncthreads();
        const int n = t;
        float accP[4] = {0.f, 0.f, 0.f, 0.f}, accQ[4] = {0.f, 0.f, 0.f, 0.f};
        for (int k = 0; k < 128; k++) {
            float w1 = ldf(We1, k * 256 + n, f32);
            float w2 = ldf(We1, (128 + k) * 256 + n, f32);
#pragma unroll
            for (int r = 0; r < 4; r++) {
                accP[r] += nf_l[r][k] * w1;
                accQ[r] += nf_l[r][k] * w2;
            }
        }
        float wx = ldf(We1, 384 * 256 + n, f32);
        float wy = ldf(We1, 385 * 256 + n, f32);
        float wz = ldf(We1, 386 * 256 + n, f32);
        float b1 = ldf(be1, n, f32);
#pragma unroll
        for (int r = 0; r < 4; r++) {
            float d = cb_l[r][0] * wx + cb_l[r][1] * wy + cb_l[r][2] * wz;
            pi2[(row0 + r) * 256 + n] = accP[r] + d + b1;
            qd[(row0 + r) * 256 + n]  = accQ[r] - d;
        }
    } else if (blk < 767) {
        // ---- T[d+255][n] = sinusoidal_pe(d) @ We1[256:384] ----
        const float d = (float)(blk - 511);           // d in [-255,255]
        if (t < 64) {
            float ang = d * 3.14159265358979323846f * exp2f(-(float)t * 0.125f);
            pe[t] = sinf(ang);
            pe[64 + t] = cosf(ang);
        }
        __syncthreads();
        float acc = 0.f;
        for (int k = 0; k < 128; k++) acc += pe[k] * ldf(We1, (256 + k) * 256 + t, f32);
        Ttab[(blk - 256) * 256 + t] = acc;
    } else {
        // ---- transpose We2, Wc1 (256x256) -> n-major, k-contiguous, f16 ----
        int tbf = blk - 767;
        int mat = tbf >> 6;
        int tb = tbf & 63;
        int bx = tb & 7, by = tb >> 3;
        const void* src = mat ? Wc1 : We2;
        u16* dst = mat ? Wc1T : We2T;
        int tx = threadIdx.x & 31, ty = threadIdx.x >> 5;
#pragma unroll
        for (int p = 0; p < 4; p++) {
            int r = by * 32 + ty + p * 8;
            tile[ty + p * 8][tx] = f2hu(ldf(src, r * 256 + bx * 32 + tx, f32));
        }
        __syncthreads();
#pragma unroll
        for (int p = 0; p < 4; p++) {
            int r = bx * 32 + ty + p * 8;
            dst[r * 256 + by * 32 + tx] = tile[tx][ty + p * 8];
        }
    }
}

// ---------------------------------------------------------------------------
// B: fused edge kernel. One WG per (b,i); loops j in 8 chunks of 32.
// KEY CHANGE vs r4: ks-loops and P1 loop limited to unroll 2 so the
// scheduler can't hoist unbounded load staging (was the spill source:
// WRITE_SIZE 155-339 MB of scratch across r0/r1/r4). No waves_per_eu pin;
// launch_bounds(256,2) only caps at 256 VGPR. Dual LDS buffers, ~38 KB.
// ---------------------------------------------------------------------------
__global__ __launch_bounds__(256, 2)
void edge_kernel(
    const int* __restrict__ resid,
    const float* __restrict__ pi2, const float* __restrict__ qd,
    const float* __restrict__ Ttab, const float* __restrict__ cbar,
    const u16* __restrict__ We2T, const u16* __restrict__ Wc1T,
    const void* __restrict__ be2, const void* __restrict__ bc1,
    const void* __restrict__ Wc2, const void* __restrict__ bc2,
    const int* __restrict__ flag,
    float* __restrict__ agg_out, float* __restrict__ cupd_out)
{
    const bool f32 = flag[0] != 0;
    const int wg = blockIdx.x;            // b*256 + i
    const int b = wg >> 8;
    const int t = threadIdx.x;
    const int lane = t & 63, w = t >> 6;  // 4 waves; wave w owns cols [64w,64w+64)
    const int c = lane & 15, q = lane >> 4;

    __shared__ __align__(16) u16 H[32][264];   // h1, f16 bits, pad +8
    __shared__ __align__(16) u16 M[32][264];   // msg, f16 bits, pad +8
    __shared__ float be2_l[256], bc1_l[256], wc2_l[256];
    __shared__ int relidx[256];
    __shared__ float fin[4][4];
    __shared__ float cbi[3];

    int ri = resid[(b << 8) + (wg & 255)];
    relidx[t] = ri - resid[(b << 8) + t] + 255;
    be2_l[t] = ldf(be2, t, f32);
    bc1_l[t] = ldf(bc1, t, f32);
    wc2_l[t] = ldf(Wc2, t, f32);
    if (t < 3) cbi[t] = cbar[wg * 3 + t];
    const float bc2q = 0.25f * ldf(bc2, 0, f32);   // bc2 folded per-wave (x4 waves)

    // phase-1 mapping: wave w owns rows [8w,8w+8); lane owns 4 k's
    const int kp = lane << 2;
    const float4 pv = *(const float4*)(pi2 + wg * 256 + kp);  // pi2 slice in regs

    float aggv[4] = {0.f, 0.f, 0.f, 0.f};          // agg cols (valid on q==0)
    float s0 = 0.f, s1 = 0.f, s2 = 0.f, s3 = 0.f;  // deferred coord partials (c==0)
    __syncthreads();

    const f32x4 zf = {0.f, 0.f, 0.f, 0.f};

    for (int jc = 0; jc < 8; jc++) {
        const int j0 = jc << 5;
        // ---- P1: H = silu(pi2[i] + qd[j] + T[rel]), f16 into LDS ----
        {
            const float* qbase = qd + ((b << 8) + j0) * 256 + kp;
            const int r0 = w * 8;
#pragma unroll 2
            for (int jj = 0; jj < 8; jj++) {
                const int j = r0 + jj;
                const float4 qv = *(const float4*)(qbase + j * 256);
                const float4 tv = *(const float4*)(Ttab + relidx[j0 + j] * 256 + kp);
                uint2 pk;
                pk.x = pkh(siluf(pv.x + qv.x + tv.x), siluf(pv.y + qv.y + tv.y));
                pk.y = pkh(siluf(pv.z + qv.z + tv.z), siluf(pv.w + qv.w + tv.w));
                *(uint2*)&H[j][kp] = pk;
            }
        }
        __syncthreads();   // S1: H complete (also: everyone left prev P3k/M)

        // ---- P2 k-loop: H @ We2 ----
        f32x4 acc[2][4];
#pragma unroll
        for (int m = 0; m < 2; m++)
#pragma unroll
            for (int n = 0; n < 4; n++) acc[m][n] = zf;
#pragma unroll 2
        for (int ks = 0; ks < 8; ks++) {
            const int kb = ks * 32 + q * 8;
            hfrag8 a[2], bb[4];
            a[0] = *(const hfrag8*)&H[c][kb];
            a[1] = *(const hfrag8*)&H[16 + c][kb];
#pragma unroll
            for (int n = 0; n < 4; n++)
                bb[n] = *(const hfrag8*)(We2T + (w * 64 + n * 16 + c) * 256 + kb);
#pragma unroll
            for (int m = 0; m < 2; m++)
#pragma unroll
                for (int n = 0; n < 4; n++)
                    acc[m][n] = __builtin_amdgcn_mfma_f32_16x16x32_f16(a[m], bb[n], acc[m][n], 0, 0, 0);
        }

        // ---- P2 epilogue: M = silu(.+be2); agg in regs (writes M, not H) ----
#pragma unroll
        for (int n = 0; n < 4; n++) {
            const int col = w * 64 + n * 16 + c;
            const float bias = be2_l[col];
            float part = 0.f;
#pragma unroll
            for (int m = 0; m < 2; m++) {
#pragma unroll
                for (int r = 0; r < 4; r++) {
                    float s = siluf(acc[m][n][r] + bias);
                    part += s;
                    M[m * 16 + q * 4 + r][col] = f2hu(s);
                }
            }
            part += __shfl_xor(part, 16);
            part += __shfl_xor(part, 32);
            aggv[n] += part;              // meaningful on q==0 lanes only
        }
        __syncthreads();   // S2: M complete

        // ---- P3 k-loop: M @ Wc1 ----
#pragma unroll
        for (int m = 0; m < 2; m++)
#pragma unroll
            for (int n = 0; n < 4; n++) acc[m][n] = zf;
#pragma unroll 2
        for (int ks = 0; ks < 8; ks++) {
            const int kb = ks * 32 + q * 8;
            hfrag8 a[2], bb[4];
            a[0] = *(const hfrag8*)&M[c][kb];
            a[1] = *(const hfrag8*)&M[16 + c][kb];
#pragma unroll
            for (int n = 0; n < 4; n++)
                bb[n] = *(const hfrag8*)(Wc1T + (w * 64 + n * 16 + c) * 256 + kb);
#pragma unroll
            for (int m = 0; m < 2; m++)
#pragma unroll
                for (int n = 0; n < 4; n++)
                    acc[m][n] = __builtin_amdgcn_mfma_f32_16x16x32_f16(a[m], bb[n], acc[m][n], 0, 0, 0);
        }

        // ---- P3 epilogue: cu row-dots; deferred distributive coord sums ----
        float dotv[2][4];
#pragma unroll
        for (int m = 0; m < 2; m++)
#pragma unroll
            for (int r = 0; r < 4; r++) dotv[m][r] = 0.f;
#pragma unroll
        for (int n = 0; n < 4; n++) {
            const int col = w * 64 + n * 16 + c;
            const float bias = bc1_l[col];
            const float wv = wc2_l[col];
#pragma unroll
            for (int m = 0; m < 2; m++)
#pragma unroll
                for (int r = 0; r < 4; r++)
                    dotv[m][r] += siluf(acc[m][n][r] + bias) * wv;
        }
#pragma unroll
        for (int m = 0; m < 2; m++) {
#pragma unroll
            for (int r = 0; r < 4; r++) {
                float v = dotv[m][r];
                v += __shfl_xor(v, 1);
                v += __shfl_xor(v, 2);
                v += __shfl_xor(v, 4);
                v += __shfl_xor(v, 8);
                if (c == 0) {   // wave-partial cu for j = j0 + m*16 + q*4 + r
                    const float vb = v + bc2q;
                    const float* cp = cbar + ((b << 8) + j0 + m * 16 + q * 4 + r) * 3;
                    s0 += vb;
                    s1 += vb * cp[0];
                    s2 += vb * cp[1];
                    s3 += vb * cp[2];
                }
            }
        }
        // no barrier needed here: next P1 writes H (nobody reads H now),
        // and M-readers all passed S2 before any wave can reach next S1.
    }

    // ---- agg out (each wave owns its 64 cols; q==0 lanes hold col sums) ----
    if (q == 0) {
#pragma unroll
        for (int n = 0; n < 4; n++)
            agg_out[wg * 256 + w * 64 + n * 16 + c] = aggv[n];
    }

    // ---- final coord reduction: one wave-reduce + 16-float LDS exchange ----
#pragma unroll
    for (int d = 1; d < 64; d <<= 1) {
        s0 += __shfl_xor(s0, d);
        s1 += __shfl_xor(s1, d);
        s2 += __shfl_xor(s2, d);
        s3 += __shfl_xor(s3, d);
    }
    if (lane == 0) { fin[w][0] = s0; fin[w][1] = s1; fin[w][2] = s2; fin[w][3] = s3; }
    __syncthreads();
    if (t == 0) {
        float S0 = fin[0][0] + fin[1][0] + fin[2][0] + fin[3][0];
        float S1 = fin[0][1] + fin[1][1] + fin[2][1] + fin[3][1];
        float S2 = fin[0][2] + fin[1][2] + fin[2][2] + fin[3][2];
        float S3 = fin[0][3] + fin[1][3] + fin[2][3] + fin[3][3];
        // coord_upd = (sum cu)*cbar_i - sum(cu*cbar_j)
        cupd_out[wg * 3 + 0] = S0 * cbi[0] - S1;
        cupd_out[wg * 3 + 1] = S0 * cbi[1] - S2;
        cupd_out[wg * 3 + 2] = S0 * cbi[2] - S3;
    }
}

// ---------------------------------------------------------------------------
// OUT (fused): blocks [0,128) = node MLP + LayerNorm -> d_out[12288..],
// blocks [128,176) = updated coords -> d_out[0..12288).
// ---------------------------------------------------------------------------
__global__ __launch_bounds__(256) void out_kernel(
    const void* __restrict__ nf, const float* __restrict__ agg,
    const void* __restrict__ Wn1, const void* __restrict__ bn1,
    const void* __restrict__ Wn2, const void* __restrict__ bn2,
    const void* __restrict__ gamma, const void* __restrict__ beta,
    const void* __restrict__ coords, const void* __restrict__ mask,
    const float* __restrict__ cupd, const int* __restrict__ flag,
    void* __restrict__ d_out)
{
    const bool f32 = flag[0] != 0;
    const int t = threadIdx.x;

    if (blockIdx.x >= 128) {
        // ---- coords part ----
        int idx = (blockIdx.x - 128) * 256 + t;
        if (idx < 4 * 256 * 4 * 3) {
            int x = idx % 3;
            int a = (idx / 3) & 3;
            int node = idx / 12;
            float v = ldf(coords, idx, f32) + cupd[node * 3 + x] * ldf(mask, node * 4 + a, f32);
            if (f32) ((float*)d_out)[idx] = v;
            else     ((u16*)d_out)[idx] = f2bu(v);
        }
        return;
    }

    // ---- node MLP + LN ----
    const int row0 = blockIdx.x * 8;
    __shared__ float x_l[8][384];
    __shared__ float hs[8][256];
    __shared__ float ho[8][128];
    for (int idx = t; idx < 8 * 384; idx += 256) {
        int r = idx / 384, k = idx % 384;
        x_l[r][k] = (k < 128) ? ldf(nf, (row0 + r) * 128 + k, f32)
                              : agg[(row0 + r) * 256 + (k - 128)];
    }
    __syncthreads();
    {
        float a1[8] = {0.f, 0.f, 0.f, 0.f, 0.f, 0.f, 0.f, 0.f};
        for (int k = 0; k < 384; k++) {
            float wv = ldf(Wn1, k * 256 + t, f32);
#pragma unroll
            for (int r = 0; r < 8; r++) a1[r] += x_l[r][k] * wv;
        }
        float b1 = ldf(bn1, t, f32);
#pragma unroll
        for (int r = 0; r < 8; r++) hs[r][t] = siluf(a1[r] + b1);
    }
    __syncthreads();
    {
        int cc = t & 127, rg = (t >> 7) * 4;
        float a2[4] = {0.f, 0.f, 0.f, 0.f};
        for (int k = 0; k < 256; k++) {
            float wv = ldf(Wn2, k * 128 + cc, f32);
#pragma unroll
            for (int r = 0; r < 4; r++) a2[r] += hs[rg + r][k] * wv;
        }
        float b2 = ldf(bn2, cc, f32);
#pragma unroll
        for (int r = 0; r < 4; r++) ho[rg + r][cc] = a2[r] + b2;
    }
    __syncthreads();
    {
        int row = t >> 5, s = t & 31;
        float sm = 0.f, sq = 0.f;
#pragma unroll
        for (int u = 0; u < 4; u++) {
            float v = ho[row][s + 32 * u];
            sm += v; sq += v * v;
        }
#pragma unroll
        for (int d = 1; d < 32; d <<= 1) {
            sm += __shfl_xor(sm, d);
            sq += __shfl_xor(sq, d);
        }
        float mu = sm * (1.f / 128.f);
        float var = sq * (1.f / 128.f) - mu * mu;
        float inv = rsqrtf(var + 1e-5f);
#pragma unroll
        for (int u = 0; u < 4; u++) {
            int cc = s + 32 * u;
            float y = (ho[row][cc] - mu) * inv;
            float outv = y * ldf(gamma, cc, f32) + ldf(beta, cc, f32);
            int oi = 12288 + (row0 + row) * 128 + cc;
            if (f32) ((float*)d_out)[oi] = outv;
            else     ((u16*)d_out)[oi] = f2bu(outv);
        }
    }
}

extern "C" void kernel_launch(void* const* d_in, const int* in_sizes, int n_in,
                              void* d_out, int out_size, void* d_ws, size_t ws_size,
                              hipStream_t stream)
{
    const void* coords = d_in[0];
    const void* nf     = d_in[1];
    const void* mask   = d_in[2];
    const int* resid   = (const int*)d_in[3];
    const void* We1 = d_in[4];
    const void* be1 = d_in[5];
    const void* We2 = d_in[6];
    const void* be2 = d_in[7];
    const void* Wn1 = d_in[8];
    const void* bn1 = d_in[9];
    const void* Wn2 = d_in[10];
    const void* bn2 = d_in[11];
    const void* gamma = d_in[12];
    const void* beta  = d_in[13];
    const void* Wc1 = d_in[14];
    const void* bc1 = d_in[15];
    const void* Wc2 = d_in[16];
    const void* bc2 = d_in[17];

    // workspace layout: [flag(16 floats pad)][f32 arrays][f16 weight arrays] ~3.96 MB
    int* flag  = (int*)d_ws;
    float* f   = (float*)d_ws + 16;
    float* cbar = f;                 // 1024*3
    float* pi2  = cbar + 3072;       // 1024*256
    float* qd   = pi2 + 262144;      // 1024*256
    float* Ttab = qd + 262144;       // 511*256
    float* agg  = Ttab + 130816;     // 1024*256
    float* cupd = agg + 262144;      // 1024*3
    u16* We2T = (u16*)(cupd + 3072); // 256*256 f16
    u16* Wc1T = We2T + 65536;        // 256*256 f16

    hipLaunchKernelGGL(detect_dtype, dim3(1), dim3(64), 0, stream, nf, flag);
    hipLaunchKernelGGL(prep_kernel, dim3(895), dim3(256), 0, stream,
                       coords, nf, We1, be1, We2, Wc1, flag, cbar, pi2, qd, Ttab, We2T, Wc1T);
    hipLaunchKernelGGL(edge_kernel, dim3(1024), dim3(256), 0, stream,
                       resid, pi2, qd, Ttab, cbar, We2T, Wc1T, be2, bc1, Wc2, bc2, flag, agg, cupd);
    hipLaunchKernelGGL(out_kernel, dim3(176), dim3(256), 0, stream,
                       nf, agg, Wn1, bn1, Wn2, bn2, gamma, beta, coords, mask, cupd, flag, d_out);
}